// Round 5
// baseline (932.750 us; speedup 1.0000x reference)
//
#include <hip/hip_runtime.h>
#include <hip/hip_bf16.h>

#define NIN    512
#define NEVAL  1536
#define NCOLS  2048
#define NOUT   256
#define OUT_BASE 1280
#define BK     64
#define NBLK   24        // NEVAL / BK
#define NROWS  16        // batch rows per WG
#define WDS    68        // Wd col stride (floats): 16B-aligned, uniform b128 reads
#define ZSTR   68        // Zc row stride (floats)

typedef __attribute__((ext_vector_type(8))) short short8;   // 8 bf16 (4 VGPRs)
typedef __attribute__((ext_vector_type(4))) float floatx4;  // MFMA C/D

#define C5 (-7.21347520444481703f)   // -5*log2(e): sigmoid(5z) = rcp(1+exp2(C5*z))

// ---------- helpers ----------

__device__ __forceinline__ unsigned short f2bf(float f) {
    __hip_bfloat16 h = __float2bfloat16(f);
    return __builtin_bit_cast(unsigned short, h);
}
__device__ __forceinline__ unsigned pack2(float a, float b) {
    return (unsigned)f2bf(a) | ((unsigned)f2bf(b) << 16);
}
// sigmoid in folded domain: y = C5*(z+b); sigma = rcp(1+exp2(y)). Overflow exact.
__device__ __forceinline__ float sig2(float y) {
    return __builtin_amdgcn_rcpf(1.0f + __builtin_amdgcn_exp2f(y));
}

// ---------- W fp32 -> bf16 (d_ws re-poisoned every launch, so rerun) ----------
// Workspace usage is EXACTLY NEVAL*NCOLS*2 bytes (proven safe in R0-R3).

__global__ __launch_bounds__(256) void wconv(const float* __restrict__ W,
                                             ushort* __restrict__ Wb, int n8) {
    int i = blockIdx.x * blockDim.x + threadIdx.x;
    if (i < n8) {
        float4 v0 = ((const float4*)W)[2 * i];
        float4 v1 = ((const float4*)W)[2 * i + 1];
        uint4 pk;
        pk.x = pack2(v0.x, v0.y); pk.y = pack2(v0.z, v0.w);
        pk.z = pack2(v1.x, v1.y); pk.w = pack2(v1.z, v1.w);
        ((uint4*)Wb)[i] = pk;
    }
}

// ---------- main kernel ----------
// ROUND-17 (= R16 lane=row chain, workspace-safe + NROWS=16):
// R16 crashed -- prime suspect: d_ws grown past its (unknown) size by the
// WdT/c5b precompute. Fix: diag-block weights staged into LDS (dbuf) by the
// 3 idle waves; workspace back to exactly Wb (proven). NROWS back to 16
// (halves per-WG Wb re-read volume vs 8; chain sigmoid serves 16 rows).
//   role 0      (1 wave): chain, lane=row (lanes 0..15 real). y[0..64) in
//               VGPRs; 1 exp2+rcp per STEP serves all 16 rows; no readlane;
//               weights = uniform b128 broadcast from Wd.
//   roles 1,2,3,5 (4 waves): mains, node-group ng, full K. Phase 1: tail(k)
//               = 2 MFMAs (B prefetched last slot) + Zc^T store. Phase 2:
//               main(k+1) over [0,512+64k) into regs + prefetch tail B(k+1).
//   roles 4,6,7 (3 waves): stagers: Wd[(k+1)&1][j*WDS+i] =
//               C5*W[64(k+1)+i][512+64(k+1)+j] (16KB, coalesced global reads).
// role4 shares the chain's SIMD (light). Slot: phase1 | beta | phase2 | alpha.
// Disjoint: mains read O cols [0,512+64k); chain writes [512+64k,+64).

__global__ __launch_bounds__(512, 2) void ffnet(const float* __restrict__ x,
                                                const float* __restrict__ W,
                                                const ushort* __restrict__ Wb,
                                                const float* __restrict__ bias,
                                                float* __restrict__ out) {
    __shared__ unsigned short O[NROWS * 2048];   // 64 KB
    __shared__ float Wd[2][64 * WDS];            // 34.8 KB dbuf diag blocks [j][i]
    __shared__ float Zc[NROWS * ZSTR];           // 4.4 KB  [row][node]

    const int t    = threadIdx.x;
    const int w    = t >> 6;        // wave 0..7
    const int lane = t & 63;

    const int cw   = (int)blockIdx.x & 7;
    const int role = (w - cw) & 7;
    const bool isMain   = (role == 1) | (role == 2) | (role == 3) | (role == 5);
    const bool isStager = (role == 4) | (role == 6) | (role == 7);
    const int ng   = (role >= 5) ? 3 : role - 1;            // valid iff isMain
    const int sidx = (role == 4) ? 0 : ((role == 6) ? 1 : 2); // valid iff isStager
    const int spt  = (sidx << 6) + lane;                    // 0..191

    // MFMA frag roles (mains)
    const int m16  = lane & 15;     // A row (batch row) / D col (node in group)
    const int quad = lane >> 4;
    const int arow = m16 << 11;
    const int arot = m16 << 3;

    // chain role: lane rr = batch row (lanes 16..63 duplicate, stores masked)
    const int rr   = lane & 15;

    // ---- stage x rows into LDS as bf16 (swizzled); 8 waves x 2 rows ----
    #pragma unroll
    for (int r2 = 0; r2 < 2; ++r2) {
        const int rs = w + (r2 << 3);
        const long rowS = (long)blockIdx.x * NROWS + rs;
        const float* xr = x + rowS * NIN + lane * 8;
        float4 v0 = *(const float4*)xr;
        float4 v1 = *(const float4*)(xr + 4);
        uint4 pk;
        pk.x = pack2(v0.x, v0.y); pk.y = pack2(v0.z, v0.w);
        pk.z = pack2(v1.x, v1.y); pk.w = pack2(v1.z, v1.w);
        *(uint4*)&O[(rs << 11) + ((lane * 8 + (rs << 3)) & 2047)] = pk;
    }
    __syncthreads();

    short8 tb0 = {}, tb1 = {};      // prefetched tail B-frags
    floatx4 accM = {0.f, 0.f, 0.f, 0.f};

    // ---- prologue (phase-2-like work for slot 0) ----
    if (isMain) {
        const ushort* wbr = Wb + (size_t)((ng << 4) + m16) * NCOLS;
        #pragma unroll 4
        for (int kk = 0; kk < NIN - BK; kk += 32) {
            short8 a = *(const short8*)&O[arow + ((kk + (quad << 3) + arot) & 2047)];
            short8 b = *(const short8*)&wbr[kk + (quad << 3)];
            accM = __builtin_amdgcn_mfma_f32_16x16x32_bf16(a, b, accM, 0, 0, 0);
        }
        tb0 = *(const short8*)&wbr[(NIN - BK) + (quad << 3)];
        tb1 = *(const short8*)&wbr[(NIN - 32) + (quad << 3)];
    } else if (isStager) {
        // stage Wd[0] for block 0: Wd[j*WDS+i] = C5*W[i][512+j]
        const float* wsrc = W + NIN;
        for (int idx = spt; idx < 4096; idx += 192) {
            const int i = idx >> 6, j = idx & 63;
            Wd[0][j * WDS + i] = C5 * wsrc[(size_t)i * NCOLS + j];
        }
    }

    for (int k = 0; k < NBLK; ++k) {
        const int i0 = k << 6;
        const int L0 = NIN + i0;

        // ===== phase 1: mains: tail(k) + Zc^T store =====
        if (isMain) {
            const int ts = L0 - BK;
            short8 a0 = *(const short8*)&O[arow + ((ts + (quad << 3) + arot) & 2047)];
            accM = __builtin_amdgcn_mfma_f32_16x16x32_bf16(a0, tb0, accM, 0, 0, 0);
            short8 a1 = *(const short8*)&O[arow + ((ts + 32 + (quad << 3) + arot) & 2047)];
            accM = __builtin_amdgcn_mfma_f32_16x16x32_bf16(a1, tb1, accM, 0, 0, 0);
            // D: lane q*16+n holds z[row 4q+p][node 16ng+n]
            const int n = (ng << 4) + m16;
            #pragma unroll
            for (int p = 0; p < 4; ++p)
                Zc[((quad << 2) + p) * ZSTR + n] = accM[p];
        }
        __syncthreads();            // beta: Zc(k) + Wd(k) visible

        if (role == 0) {
            // ===== chain: block k, lane=row, 64-step triangle =====
            float y[64];
            {
                const float* zr = &Zc[rr * ZSTR];
                const float* bb = bias + i0;    // uniform -> s_load
                #pragma unroll
                for (int m = 0; m < 16; ++m) {
                    floatx4 zv = *(const floatx4*)(zr + (m << 2));
                    y[(m << 2) + 0] = C5 * (zv.x + bb[(m << 2) + 0]);
                    y[(m << 2) + 1] = C5 * (zv.y + bb[(m << 2) + 1]);
                    y[(m << 2) + 2] = C5 * (zv.z + bb[(m << 2) + 2]);
                    y[(m << 2) + 3] = C5 * (zv.w + bb[(m << 2) + 3]);
                }
            }
            const float* wd = &Wd[k & 1][0];
            #pragma unroll
            for (int j0 = 0; j0 < 64; j0 += 8) {
                float of[8];
                #pragma unroll
                for (int js = 0; js < 8; ++js) {
                    const int j = j0 + js;
                    const float o = sig2(y[j]);     // y[j] final after step j-1
                    of[js] = o;
                    const float* wc = wd + j * WDS; // uniform -> broadcast reads
                    const int ib = (j + 1) & ~3;
                    #pragma unroll
                    for (int i4 = ib; i4 < 64; i4 += 4) {
                        floatx4 wv = *(const floatx4*)(wc + i4);
                        if (i4 + 0 > j) y[i4 + 0] = fmaf(wv.x, o, y[i4 + 0]);
                        if (i4 + 1 > j) y[i4 + 1] = fmaf(wv.y, o, y[i4 + 1]);
                        if (i4 + 2 > j) y[i4 + 2] = fmaf(wv.z, o, y[i4 + 2]);
                        if (i4 + 3 > j) y[i4 + 3] = fmaf(wv.w, o, y[i4 + 3]);
                    }
                }
                if (lane < NROWS) {
                    uint4 pk;
                    pk.x = pack2(of[0], of[1]); pk.y = pack2(of[2], of[3]);
                    pk.z = pack2(of[4], of[5]); pk.w = pack2(of[6], of[7]);
                    *(uint4*)&O[(rr << 11) + ((L0 + j0 + (rr << 3)) & 2047)] = pk;
                    if (k >= 20) {      // blocks 20..23 = output nodes
                        float* op = out + ((long)blockIdx.x * NROWS + rr) * NOUT
                                        + (i0 - OUT_BASE) + j0;
                        *(float4*)op       = float4{of[0], of[1], of[2], of[3]};
                        *(float4*)(op + 4) = float4{of[4], of[5], of[6], of[7]};
                    }
                }
            }
        } else if (isMain && k + 1 < NBLK) {
            // ===== mains: main(k+1) over [0, 512+64k) + tail-B prefetch =====
            const int b = k + 1;
            const ushort* wbr = Wb + (size_t)((b << 6) + (ng << 4) + m16) * NCOLS;
            const int ts = NIN + (b << 6) - BK;
            tb0 = *(const short8*)&wbr[ts + (quad << 3)];
            tb1 = *(const short8*)&wbr[ts + 32 + (quad << 3)];
            floatx4 z = {0.f, 0.f, 0.f, 0.f};
            const int hi = NIN + i0;
            #pragma unroll 4
            for (int kk = 0; kk < hi; kk += 32) {
                short8 a  = *(const short8*)&O[arow + ((kk + (quad << 3) + arot) & 2047)];
                short8 bf = *(const short8*)&wbr[kk + (quad << 3)];
                z = __builtin_amdgcn_mfma_f32_16x16x32_bf16(a, bf, z, 0, 0, 0);
            }
            accM = z;
        } else if (isStager && k + 1 < NBLK) {
            // ===== stagers: Wd[(k+1)&1] = C5 * diag-block(k+1), transposed =====
            const int b = k + 1;
            float* wdn = &Wd[b & 1][0];
            const float* wsrc = W + (size_t)(b << 6) * NCOLS + (NIN + (b << 6));
            for (int idx = spt; idx < 4096; idx += 192) {
                const int i = idx >> 6, j = idx & 63;
                wdn[j * WDS + i] = C5 * wsrc[(size_t)i * NCOLS + j];
            }
        }
        __syncthreads();            // alpha: O(k) visible; Zc/Wd consumed
    }
}

// ---------- launch ----------

extern "C" void kernel_launch(void* const* d_in, const int* in_sizes, int n_in,
                              void* d_out, int out_size, void* d_ws, size_t ws_size,
                              hipStream_t stream) {
    const float* x  = (const float*)d_in[0];   // [4096, 512]
    const float* W  = (const float*)d_in[1];   // [1536, 2048]
    const float* b  = (const float*)d_in[2];   // [1536]
    float* out = (float*)d_out;                // [4096, 256]
    ushort* Wb = (ushort*)d_ws;                // bf16 W copy (6.29 MB, exact R0-R3 usage)

    int n8 = NEVAL * NCOLS / 8;
    wconv<<<n8 / 256, 256, 0, stream>>>(W, Wb, n8);
    ffnet<<<4096 / NROWS, 512, 0, stream>>>(x, W, Wb, b, out);
}

// Round 6
// 932.270 us; speedup vs baseline: 1.0005x; 1.0005x over previous
//
#include <hip/hip_runtime.h>
#include <hip/hip_bf16.h>

#define NIN    512
#define NEVAL  1536
#define NCOLS  2048
#define NOUT   256
#define OUT_BASE 1280
#define BK     64
#define NBLK   24        // NEVAL / BK
#define NROWS  16        // batch rows per WG
#define WDS    68        // Wd col stride (floats): 16B-aligned, uniform b128 reads
#define ZSTR   68        // Zc row stride (floats)

typedef __attribute__((ext_vector_type(8))) short short8;   // 8 bf16 (4 VGPRs)
typedef __attribute__((ext_vector_type(4))) float floatx4;  // MFMA C/D

#define C5 (-7.21347520444481703f)   // -5*log2(e): sigmoid(5z) = rcp(1+exp2(C5*z))

// ---------- helpers ----------

__device__ __forceinline__ unsigned short f2bf(float f) {
    __hip_bfloat16 h = __float2bfloat16(f);
    return __builtin_bit_cast(unsigned short, h);
}
__device__ __forceinline__ unsigned pack2(float a, float b) {
    return (unsigned)f2bf(a) | ((unsigned)f2bf(b) << 16);
}
// sigmoid in folded domain: y = C5*(z+b); sigma = rcp(1+exp2(y)). Overflow exact.
__device__ __forceinline__ float sig2(float y) {
    return __builtin_amdgcn_rcpf(1.0f + __builtin_amdgcn_exp2f(y));
}

// ---------- W fp32 -> bf16 (d_ws re-poisoned every launch, so rerun) ----------
// Workspace usage is EXACTLY NEVAL*NCOLS*2 bytes (proven safe).

__global__ __launch_bounds__(256) void wconv(const float* __restrict__ W,
                                             ushort* __restrict__ Wb, int n8) {
    int i = blockIdx.x * blockDim.x + threadIdx.x;
    if (i < n8) {
        float4 v0 = ((const float4*)W)[2 * i];
        float4 v1 = ((const float4*)W)[2 * i + 1];
        uint4 pk;
        pk.x = pack2(v0.x, v0.y); pk.y = pack2(v0.z, v0.w);
        pk.z = pack2(v1.x, v1.y); pk.w = pack2(v1.z, v1.w);
        ((uint4*)Wb)[i] = pk;
    }
}

// ---------- main kernel ----------
// ROUND-18: R17 structure, spill fixed. R17's launch_bounds(512,2) capped
// VGPR at 128 (2nd arg = min waves/EU) -> chain's y[64] spilled to scratch
// (VGPR=124 at cap, WRITE_SIZE doubled by 4MB scratch writeback, all pipes
// idle at 885us: ~200cyc spill latency in the SERIAL triangle). LDS
// (102.5KB) already binds occupancy to 1 WG/CU = 2 waves/SIMD, which a
// 256-VGPR cap permits -> launch_bounds(512,1).
//   role 0      (1 wave): chain, lane=row (lanes 0..15 real). y[0..64) in
//               VGPRs; 1 exp2+rcp per STEP serves all 16 rows; no readlane;
//               weights = uniform b128 broadcast from Wd.
//   roles 1,2,3,5 (4 waves): mains, node-group ng, full K. Phase 1: tail(k)
//               = 2 MFMAs (B prefetched last slot) + Zc^T store. Phase 2:
//               main(k+1) over [0,512+64k) into regs + prefetch tail B(k+1).
//   roles 4,6,7 (3 waves): stagers: Wd[(k+1)&1][j*WDS+i] =
//               C5*W[64(k+1)+i][512+64(k+1)+j] (16KB, coalesced global reads).
// Slot: phase1 | beta | phase2 | alpha. Disjoint: mains read O cols
// [0,512+64k); chain writes [512+64k,+64).

__global__ __launch_bounds__(512, 1) void ffnet(const float* __restrict__ x,
                                                const float* __restrict__ W,
                                                const ushort* __restrict__ Wb,
                                                const float* __restrict__ bias,
                                                float* __restrict__ out) {
    __shared__ unsigned short O[NROWS * 2048];   // 64 KB
    __shared__ float Wd[2][64 * WDS];            // 34.8 KB dbuf diag blocks [j][i]
    __shared__ float Zc[NROWS * ZSTR];           // 4.4 KB  [row][node]

    const int t    = threadIdx.x;
    const int w    = t >> 6;        // wave 0..7
    const int lane = t & 63;

    const int cw   = (int)blockIdx.x & 7;
    const int role = (w - cw) & 7;
    const bool isMain   = (role == 1) | (role == 2) | (role == 3) | (role == 5);
    const bool isStager = (role == 4) | (role == 6) | (role == 7);
    const int ng   = (role >= 5) ? 3 : role - 1;              // valid iff isMain
    const int sidx = (role == 4) ? 0 : ((role == 6) ? 1 : 2); // valid iff isStager
    const int spt  = (sidx << 6) + lane;                      // 0..191

    // MFMA frag roles (mains)
    const int m16  = lane & 15;     // A row (batch row) / D col (node in group)
    const int quad = lane >> 4;
    const int arow = m16 << 11;
    const int arot = m16 << 3;

    // chain role: lane rr = batch row (lanes 16..63 duplicate, stores masked)
    const int rr   = lane & 15;

    // ---- stage x rows into LDS as bf16 (swizzled); 8 waves x 2 rows ----
    #pragma unroll
    for (int r2 = 0; r2 < 2; ++r2) {
        const int rs = w + (r2 << 3);
        const long rowS = (long)blockIdx.x * NROWS + rs;
        const float* xr = x + rowS * NIN + lane * 8;
        float4 v0 = *(const float4*)xr;
        float4 v1 = *(const float4*)(xr + 4);
        uint4 pk;
        pk.x = pack2(v0.x, v0.y); pk.y = pack2(v0.z, v0.w);
        pk.z = pack2(v1.x, v1.y); pk.w = pack2(v1.z, v1.w);
        *(uint4*)&O[(rs << 11) + ((lane * 8 + (rs << 3)) & 2047)] = pk;
    }
    __syncthreads();

    short8 tb0 = {}, tb1 = {};      // prefetched tail B-frags
    floatx4 accM = {0.f, 0.f, 0.f, 0.f};

    // ---- prologue (phase-2-like work for slot 0) ----
    if (isMain) {
        const ushort* wbr = Wb + (size_t)((ng << 4) + m16) * NCOLS;
        #pragma unroll 4
        for (int kk = 0; kk < NIN - BK; kk += 32) {
            short8 a = *(const short8*)&O[arow + ((kk + (quad << 3) + arot) & 2047)];
            short8 b = *(const short8*)&wbr[kk + (quad << 3)];
            accM = __builtin_amdgcn_mfma_f32_16x16x32_bf16(a, b, accM, 0, 0, 0);
        }
        tb0 = *(const short8*)&wbr[(NIN - BK) + (quad << 3)];
        tb1 = *(const short8*)&wbr[(NIN - 32) + (quad << 3)];
    } else if (isStager) {
        // stage Wd[0] for block 0: Wd[j*WDS+i] = C5*W[i][512+j]
        const float* wsrc = W + NIN;
        for (int idx = spt; idx < 4096; idx += 192) {
            const int i = idx >> 6, j = idx & 63;
            Wd[0][j * WDS + i] = C5 * wsrc[(size_t)i * NCOLS + j];
        }
    }

    for (int k = 0; k < NBLK; ++k) {
        const int i0 = k << 6;
        const int L0 = NIN + i0;

        // ===== phase 1: mains: tail(k) + Zc^T store =====
        if (isMain) {
            const int ts = L0 - BK;
            short8 a0 = *(const short8*)&O[arow + ((ts + (quad << 3) + arot) & 2047)];
            accM = __builtin_amdgcn_mfma_f32_16x16x32_bf16(a0, tb0, accM, 0, 0, 0);
            short8 a1 = *(const short8*)&O[arow + ((ts + 32 + (quad << 3) + arot) & 2047)];
            accM = __builtin_amdgcn_mfma_f32_16x16x32_bf16(a1, tb1, accM, 0, 0, 0);
            // D: lane q*16+n holds z[row 4q+p][node 16ng+n]
            const int n = (ng << 4) + m16;
            #pragma unroll
            for (int p = 0; p < 4; ++p)
                Zc[((quad << 2) + p) * ZSTR + n] = accM[p];
        }
        __syncthreads();            // beta: Zc(k) + Wd(k) visible

        if (role == 0) {
            // ===== chain: block k, lane=row, 64-step triangle =====
            float y[64];
            {
                const float* zr = &Zc[rr * ZSTR];
                const float* bb = bias + i0;    // uniform -> s_load
                #pragma unroll
                for (int m = 0; m < 16; ++m) {
                    floatx4 zv = *(const floatx4*)(zr + (m << 2));
                    y[(m << 2) + 0] = C5 * (zv.x + bb[(m << 2) + 0]);
                    y[(m << 2) + 1] = C5 * (zv.y + bb[(m << 2) + 1]);
                    y[(m << 2) + 2] = C5 * (zv.z + bb[(m << 2) + 2]);
                    y[(m << 2) + 3] = C5 * (zv.w + bb[(m << 2) + 3]);
                }
            }
            const float* wd = &Wd[k & 1][0];
            #pragma unroll
            for (int j0 = 0; j0 < 64; j0 += 8) {
                float of[8];
                #pragma unroll
                for (int js = 0; js < 8; ++js) {
                    const int j = j0 + js;
                    const float o = sig2(y[j]);     // y[j] final after step j-1
                    of[js] = o;
                    const float* wc = wd + j * WDS; // uniform -> broadcast reads
                    const int ib = (j + 1) & ~3;
                    #pragma unroll
                    for (int i4 = ib; i4 < 64; i4 += 4) {
                        floatx4 wv = *(const floatx4*)(wc + i4);
                        if (i4 + 0 > j) y[i4 + 0] = fmaf(wv.x, o, y[i4 + 0]);
                        if (i4 + 1 > j) y[i4 + 1] = fmaf(wv.y, o, y[i4 + 1]);
                        if (i4 + 2 > j) y[i4 + 2] = fmaf(wv.z, o, y[i4 + 2]);
                        if (i4 + 3 > j) y[i4 + 3] = fmaf(wv.w, o, y[i4 + 3]);
                    }
                }
                if (lane < NROWS) {
                    uint4 pk;
                    pk.x = pack2(of[0], of[1]); pk.y = pack2(of[2], of[3]);
                    pk.z = pack2(of[4], of[5]); pk.w = pack2(of[6], of[7]);
                    *(uint4*)&O[(rr << 11) + ((L0 + j0 + (rr << 3)) & 2047)] = pk;
                    if (k >= 20) {      // blocks 20..23 = output nodes
                        float* op = out + ((long)blockIdx.x * NROWS + rr) * NOUT
                                        + (i0 - OUT_BASE) + j0;
                        *(float4*)op       = float4{of[0], of[1], of[2], of[3]};
                        *(float4*)(op + 4) = float4{of[4], of[5], of[6], of[7]};
                    }
                }
            }
        } else if (isMain && k + 1 < NBLK) {
            // ===== mains: main(k+1) over [0, 512+64k) + tail-B prefetch =====
            const int b = k + 1;
            const ushort* wbr = Wb + (size_t)((b << 6) + (ng << 4) + m16) * NCOLS;
            const int ts = NIN + (b << 6) - BK;
            tb0 = *(const short8*)&wbr[ts + (quad << 3)];
            tb1 = *(const short8*)&wbr[ts + 32 + (quad << 3)];
            floatx4 z = {0.f, 0.f, 0.f, 0.f};
            const int hi = NIN + i0;
            #pragma unroll 4
            for (int kk = 0; kk < hi; kk += 32) {
                short8 a  = *(const short8*)&O[arow + ((kk + (quad << 3) + arot) & 2047)];
                short8 bf = *(const short8*)&wbr[kk + (quad << 3)];
                z = __builtin_amdgcn_mfma_f32_16x16x32_bf16(a, bf, z, 0, 0, 0);
            }
            accM = z;
        } else if (isStager && k + 1 < NBLK) {
            // ===== stagers: Wd[(k+1)&1] = C5 * diag-block(k+1), transposed =====
            const int b = k + 1;
            float* wdn = &Wd[b & 1][0];
            const float* wsrc = W + (size_t)(b << 6) * NCOLS + (NIN + (b << 6));
            for (int idx = spt; idx < 4096; idx += 192) {
                const int i = idx >> 6, j = idx & 63;
                wdn[j * WDS + i] = C5 * wsrc[(size_t)i * NCOLS + j];
            }
        }
        __syncthreads();            // alpha: O(k) visible; Zc/Wd consumed
    }
}

// ---------- launch ----------

extern "C" void kernel_launch(void* const* d_in, const int* in_sizes, int n_in,
                              void* d_out, int out_size, void* d_ws, size_t ws_size,
                              hipStream_t stream) {
    const float* x  = (const float*)d_in[0];   // [4096, 512]
    const float* W  = (const float*)d_in[1];   // [1536, 2048]
    const float* b  = (const float*)d_in[2];   // [1536]
    float* out = (float*)d_out;                // [4096, 256]
    ushort* Wb = (ushort*)d_ws;                // bf16 W copy (6.29 MB, exact proven usage)

    int n8 = NEVAL * NCOLS / 8;
    wconv<<<n8 / 256, 256, 0, stream>>>(W, Wb, n8);
    ffnet<<<4096 / NROWS, 512, 0, stream>>>(x, W, Wb, b, out);
}